// Round 8
// baseline (384.482 us; speedup 1.0000x reference)
//
#include <hip/hip_runtime.h>
#include <hip/hip_bf16.h>

typedef float  f32x4  __attribute__((ext_vector_type(4)));
typedef short  bf16x8 __attribute__((ext_vector_type(8)));
typedef short  s16x4  __attribute__((ext_vector_type(4)));

// HW bf16 converts (RNE) — used in kT/k2 (measured good in R2).
__device__ __forceinline__ unsigned short f2bf(float f) {
    __hip_bfloat16 h = __float2bfloat16(f);
    return *reinterpret_cast<unsigned short*>(&h);
}
__device__ __forceinline__ unsigned int f2bf2(float a, float b) {
    __hip_bfloat162 h = __float22bfloat162_rn(make_float2(a, b));
    return *reinterpret_cast<unsigned int*>(&h);
}
// Manual RNE bit-trick — used in kF (part of the measured-62µs structure).
__device__ __forceinline__ unsigned short f2bf_bit(float f) {
    unsigned int u = __float_as_uint(f);
    unsigned int r = (u + 0x7FFFu + ((u >> 16) & 1u)) >> 16;
    return (unsigned short)r;
}
__device__ __forceinline__ float bf2f(unsigned short h) {
    return __uint_as_float(((unsigned int)h) << 16);
}

// ---------------------------------------------------------------------------
// KT: x (fp32 [c][pos]) -> xT (bf16 [pos][c], channel-last) + t-mean PARTIALS
// (no atomics). grid (32,32,2), 256 thr. LDS stride 226.
// ---------------------------------------------------------------------------
__global__ __launch_bounds__(256) void kT_transpose(
    const float* __restrict__ x1, const float* __restrict__ x2,
    float* __restrict__ xmp, unsigned short* __restrict__ xT)
{
    const int tc = blockIdx.x, n = blockIdx.y, p = blockIdx.z;
    const float* __restrict__ x = p ? x2 : x1;
    __shared__ unsigned short tile[64 * 226];   // [c][pos 200, stride 226]
    const int tid = threadIdx.x;

    const size_t xb = (size_t)n * 409600 + (size_t)tc * 200;
    for (int k = 0; k < 13; k++) {
        const int idx = tid + k * 256;
        if (idx < 3200) {
            const int c = idx / 50, l = idx % 50;
            const f32x4 v = *(const f32x4*)(x + xb + (size_t)c * 6400 + l * 4);
            unsigned int* dst = (unsigned int*)&tile[c * 226 + l * 4];
            dst[0] = f2bf2(v[0], v[1]);
            dst[1] = f2bf2(v[2], v[3]);
        }
    }
    __syncthreads();

    // mean partials over this chunk's 8 t's -> coalesced row store (no atomics)
    for (int k = 0; k < 7; k++) {
        const int idx = tid + k * 256;
        if (idx < 1600) {
            const int c = idx / 25, v = idx % 25;
            float s = 0.f;
            #pragma unroll
            for (int t = 0; t < 8; t++) s += bf2f(tile[c * 226 + t * 25 + v]);
            xmp[((size_t)((p * 32 + n) * 32 + tc)) * 1600 + idx] =
                s * (1.0f / 256.0f);
        }
    }

    // store phase: gather 8 channels per lane -> coalesced bf16x8 stores
    for (int k = 0; k < 7; k++) {
        const int idx = tid + k * 256;
        if (idx < 1600) {
            const int c8 = idx & 7, pos = idx >> 3;
            bf16x8 o;
            #pragma unroll
            for (int j = 0; j < 8; j++)
                o[j] = (short)tile[(c8 * 8 + j) * 226 + pos];
            *(bf16x8*)(xT + (((size_t)(p * 32 + n) * 6400 + tc * 200 + pos) * 64
                             + c8 * 8)) = o;
        }
    }
}

// ---------------------------------------------------------------------------
// K2a: xmp (32 partials) -> xm -> r1/r2 -> rel -> relg (global, (i,n)-indexed).
// grid 102: blocks 0..95 = (i,n); 96..101 = conv3/conv4 weight pack.
// ---------------------------------------------------------------------------
__global__ __launch_bounds__(256) void k2a_rel(
    const float* __restrict__ xmp,
    const float* __restrict__ c1w, const float* __restrict__ c1b,
    const float* __restrict__ c2w, const float* __restrict__ c2b,
    float* __restrict__ relg,
    const float* __restrict__ c3w, const float* __restrict__ c4w,
    unsigned short* __restrict__ awW)
{
    const int b = blockIdx.x;
    const int tid = threadIdx.x;

    if (b >= 96) {                       // ---- weight pack (6 blocks) ----
        const int pi = b - 96;           // p*3+i
        const int p = pi / 3, i = pi % 3;
        const int cg = tid >> 6, lane = tid & 63, q = lane >> 4, m = lane & 15;
        const float* w3 = p ? c4w : c3w;
        const float* wr = w3 + (size_t)(i * 64 + cg * 16 + m) * 64 + q * 8;
        const f32x4 w00 = *(const f32x4*)(wr);
        const f32x4 w01 = *(const f32x4*)(wr + 4);
        const f32x4 w10 = *(const f32x4*)(wr + 32);
        const f32x4 w11 = *(const f32x4*)(wr + 36);
        bf16x8 af0, af1;
        #pragma unroll
        for (int k = 0; k < 4; k++) {
            af0[k] = (short)f2bf(w00[k]); af0[k + 4] = (short)f2bf(w01[k]);
            af1[k] = (short)f2bf(w10[k]); af1[k + 4] = (short)f2bf(w11[k]);
        }
        unsigned short* o = awW + ((size_t)(pi * 4 + cg) * 64 + lane) * 16;
        *(bf16x8*)(o)     = af0;
        *(bf16x8*)(o + 8) = af1;
        return;
    }

    const int i = b >> 5, n = b & 31;
    __shared__ float xml[3200];
    __shared__ float rl[400];

    // reduce 32 tc-partials (coalesced vec4 rows) -> xm in LDS
    for (int idx = tid; idx < 800; idx += 256) {
        const int p_ = idx / 400, r4 = (idx % 400) * 4;
        f32x4 s = (f32x4){0.f, 0.f, 0.f, 0.f};
        #pragma unroll 4
        for (int tcc = 0; tcc < 32; tcc++)
            s += *(const f32x4*)(xmp + ((size_t)((p_ * 32 + n) * 32 + tcc)) * 1600 + r4);
        *(f32x4*)(xml + p_ * 1600 + r4) = s;
    }
    __syncthreads();

    // r1/r2: 400 dot products of length 64
    for (int idx = tid; idx < 400; idx += 256) {
        const int which = idx / 200;
        const int rr = (idx % 200) / 25;
        const int v = idx % 25;
        const float* wv = (which ? c2w : c1w) + (i * 8 + rr) * 64;
        const float* xp = xml + which * 1600;
        float s = (which ? c2b : c1b)[i * 8 + rr];
        for (int c = 0; c < 64; c++) s += wv[c] * xp[c * 25 + v];
        rl[idx] = s;
    }
    __syncthreads();

    // rel = tanh(r1[u] - r2[v]) -> global, coalesced
    for (int idx = tid; idx < 5000; idx += 256) {
        const int r_ = idx / 625;
        const int rem = idx - r_ * 625;
        const int u = rem / 25;
        const int v = rem - u * 25;
        relg[(size_t)b * 5024 + idx] =
            tanhf(rl[r_ * 25 + u] - rl[200 + r_ * 25 + v]);
    }
}

// ---------------------------------------------------------------------------
// K2b: relg -> a packed as MFMA B-fragments (bf16, zero-padded).
// grid 1536 = (i:3, n:32, pp:2, cq:8); each block packs 8 channels.
// ---------------------------------------------------------------------------
__global__ __launch_bounds__(256) void k2b_pack(
    const float* __restrict__ relg,
    const float* __restrict__ PA, const float* __restrict__ alpha,
    const float* __restrict__ c5w, const float* __restrict__ c5b,
    const float* __restrict__ c6w, const float* __restrict__ c6b,
    unsigned short* __restrict__ aw)
{
    const int b = blockIdx.x;
    const int cq = b & 7;
    const int pp = (b >> 3) & 1;
    const int n  = (b >> 4) & 31;
    const int i  = b >> 9;
    const int tid = threadIdx.x;

    __shared__ float rel[5000];
    const float* rsrc = relg + (size_t)(i * 32 + n) * 5024;
    for (int idx = tid; idx < 1250; idx += 256)
        *(f32x4*)(&rel[idx * 4]) = *(const f32x4*)(rsrc + idx * 4);
    __syncthreads();

    const float al = alpha[0];
    const float* w5 = pp ? c6w : c5w;
    const float* b5 = pp ? c6b : c5b;

    #pragma unroll
    for (int k = 0; k < 4; k++) {
        const int item = tid + k * 256;      // 0..1023
        const int cc = item >> 7;            // 0..7
        const int c  = cq * 8 + cc;
        const int ut = (item >> 6) & 1;
        const int lane = item & 63;
        const int u = ut * 16 + (lane & 15);
        const int qd = lane >> 4;
        bf16x8 outv;
        if (u < 25) {
            float wrow[8];
            #pragma unroll
            for (int r = 0; r < 8; r++) wrow[r] = w5[(i * 64 + c) * 8 + r];
            const float bias = b5[i * 64 + c];
            #pragma unroll
            for (int j = 0; j < 8; j++) {
                const int v = qd * 8 + j;
                float s = 0.f;
                if (v < 25) {
                    s = bias + (pp ? al : PA[i * 625 + u * 25 + v]);
                    #pragma unroll
                    for (int r = 0; r < 8; r++)
                        s += rel[r * 625 + u * 25 + v] * wrow[r];
                }
                outv[j] = (short)f2bf(s);
            }
        } else {
            #pragma unroll
            for (int j = 0; j < 8; j++) outv[j] = 0;
        }
        *(bf16x8*)(aw + ((size_t)((pp * 3 + i) * 32 + n) * 64 + c) * 1024
                      + ut * 512 + lane * 8) = outv;
    }
}

// ---------------------------------------------------------------------------
// KF v6: unified-register occupancy fix. R7 showed LDS is not the residency
// cap; the unified VGPR+AGPR total (~84 reported + 32 acc + frags ≈ 148) put
// us in the 129-256 bracket = 2 waves/SIMD = 2 blocks/CU. Fix: drop the
// 56-VGPR xr hoist (stage1 reads xT in-loop; the XCD-L2-resident slice makes
// re-reads ~200-400cy L2 hits, hidden under loop work) and pin the budget
// with __launch_bounds__(256,4) (total <=128 -> 4 blocks/CU).
// R3's spill disaster came from the hoist's 148 live values fighting the 64-
// VGPR cap; without the hoist, the natural live set fits (R0: VGPR 52).
// Tripwire: WRITE_SIZE >> 52MB = spills -> revert.
// ---------------------------------------------------------------------------
__global__ __launch_bounds__(256, 4) void kF_main(
    const unsigned short* __restrict__ xT,
    const float* __restrict__ c3b, const float* __restrict__ c4b,
    const unsigned short* __restrict__ awW,
    const unsigned short* __restrict__ aw,
    unsigned short* __restrict__ z,
    float* __restrict__ ppart)
{
    // XCD-aware decode (bijective): xcd = flat&7 under round-robin dispatch.
    const int flat = blockIdx.x;
    const int lidx = flat >> 3;                      // 0..511
    const int grp  = (flat & 7) * 8 + (lidx >> 6);   // 0..63 = (n,p) group
    const int within = lidx & 63;
    const int tc = within & 15, cg = within >> 4;
    const int n = grp & 31, p = grp >> 5;

    __shared__ unsigned short X3s[16 * 512];         // single buffer, 16 KB
    const int tid = threadIdx.x, w = tid >> 6, lane = tid & 63;
    const int q = lane >> 4, m = lane & 15;

    {   // zero once: provides v=25..31 zero padding forever
        int* xi = (int*)X3s;
        #pragma unroll
        for (int k = 0; k < 16; k++) xi[tid + k * 256] = 0;
    }

    const float* __restrict__ b3 = p ? c4b : c3b;
    const unsigned short* __restrict__ xbase =
        xT + ((size_t)(p * 32 + n) * 6400 + (size_t)tc * 400) * 64;

    f32x4 acc[4][2];
    #pragma unroll
    for (int a = 0; a < 4; a++) {
        acc[a][0] = (f32x4){0.f, 0.f, 0.f, 0.f};
        acc[a][1] = (f32x4){0.f, 0.f, 0.f, 0.f};
    }

    __syncthreads();   // zero-fill visible to all waves

    for (int i = 0; i < 3; i++) {
        // ---- prefetch stage-2 B-fragments (consumed after the barrier) ----
        bf16x8 B0[4], B1[4];
        #pragma unroll
        for (int cl4 = 0; cl4 < 4; cl4++) {
            const int c = cg * 16 + w * 4 + cl4;
            const unsigned short* ab =
                aw + ((size_t)((p * 3 + i) * 32 + n) * 64 + c) * 1024 + lane * 8;
            B0[cl4] = *(const bf16x8*)(ab);
            B1[cl4] = *(const bf16x8*)(ab + 512);
        }

        // ---- stage 1: X3 = W3*x + b, xT read in-loop (XCD-L2 resident) ----
        const unsigned short* wp =
            awW + ((size_t)((p * 3 + i) * 4 + cg) * 64 + lane) * 16;
        const bf16x8 af0 = *(const bf16x8*)(wp);
        const bf16x8 af1 = *(const bf16x8*)(wp + 8);
        float bb[4];
        #pragma unroll
        for (int r = 0; r < 4; r++) bb[r] = b3[i * 64 + cg * 16 + q * 4 + r];

        #pragma unroll
        for (int k = 0; k < 7; k++) {
            const int g = w + 4 * k;
            if (g < 25) {
                const unsigned short* xp = xbase + (size_t)(g * 16 + m) * 64 + q * 8;
                const bf16x8 xb0 = *(const bf16x8*)(xp);
                const bf16x8 xb1 = *(const bf16x8*)(xp + 32);
                f32x4 d = (f32x4){0.f, 0.f, 0.f, 0.f};
                d = __builtin_amdgcn_mfma_f32_16x16x32_bf16(af0, xb0, d, 0, 0, 0);
                d = __builtin_amdgcn_mfma_f32_16x16x32_bf16(af1, xb1, d, 0, 0, 0);
                const int pos = g * 16 + m;
                const int t = pos / 25, v = pos - t * 25;
                #pragma unroll
                for (int r = 0; r < 4; r++)
                    X3s[(q * 4 + r) * 512 + t * 32 + v] = f2bf_bit(d[r] + bb[r]);
            }
        }
        __syncthreads();

        // ---- stage 2: Z[c][t][u] += X3[c][t][v] * a[c][u][v] ----
        #pragma unroll
        for (int cl4 = 0; cl4 < 4; cl4++) {
            const int cl = w * 4 + cl4;
            const bf16x8 A = *(const bf16x8*)(X3s + cl * 512 + m * 32 + q * 8);
            acc[cl4][0] = __builtin_amdgcn_mfma_f32_16x16x32_bf16(A, B0[cl4], acc[cl4][0], 0, 0, 0);
            acc[cl4][1] = __builtin_amdgcn_mfma_f32_16x16x32_bf16(A, B1[cl4], acc[cl4][1], 0, 0, 0);
        }
        __syncthreads();   // X3s overwritten next i / reused by epilogue
    }

    // ---- epilogue: stats partials + coalesced z store via LDS transpose ----
    unsigned short* stg = X3s;          // staging: 4 waves x 1600 u16
    #pragma unroll
    for (int cl4 = 0; cl4 < 4; cl4++) {
        float sum = 0.f, ssq = 0.f;
        #pragma unroll
        for (int r = 0; r < 4; r++) {
            const float v0 = acc[cl4][0][r];
            sum += v0; ssq += v0 * v0;
        }
        if (m < 9) {
            #pragma unroll
            for (int r = 0; r < 4; r++) {
                const float v1 = acc[cl4][1][r];
                sum += v1; ssq += v1 * v1;
            }
        }
        #pragma unroll
        for (int off = 32; off > 0; off >>= 1) {
            sum += __shfl_xor(sum, off, 64);
            ssq += __shfl_xor(ssq, off, 64);
        }
        const int c = cg * 16 + w * 4 + cl4;
        if (lane == 0) {
            float* pp = ppart + ((size_t)(p * 64 + c) * 512 + n * 16 + tc) * 2;
            pp[0] = sum; pp[1] = ssq;
        }
        // scatter into wave-private staging (no barrier needed: wave-private)
        #pragma unroll
        for (int ut = 0; ut < 2; ut++) {
            if (ut == 0 || m < 9) {
                #pragma unroll
                for (int r = 0; r < 4; r++)
                    stg[w * 1600 + cl4 * 400 + (q * 4 + r) * 25 + ut * 16 + m] =
                        f2bf_bit(acc[cl4][ut][r]);
            }
        }
    }
    // coalesced read-back + 16B global stores (wave-private region)
    for (int rd = 0; rd < 4; rd++) {
        const int idx = rd * 64 + lane;
        if (idx < 200) {
            const int cl4 = idx / 50, oct = idx % 50;
            const bf16x8 vz = *(const bf16x8*)(stg + w * 1600 + cl4 * 400 + oct * 8);
            const int c = cg * 16 + w * 4 + cl4;
            *(bf16x8*)(z + ((size_t)((p * 32 + n) * 64 + c)) * 6400
                         + tc * 400 + oct * 8) = vz;
        }
    }
}

// ---------------------------------------------------------------------------
// K4: reduce ppart (512 partials per (p,c)) -> per-channel scale/shift.
// ---------------------------------------------------------------------------
__global__ void k4_finalize(const float* __restrict__ ppart,
                            const float* __restrict__ bn1w, const float* __restrict__ bn1b,
                            const float* __restrict__ bn2w, const float* __restrict__ bn2b,
                            float* __restrict__ ss)
{
    const int b = blockIdx.x;            // p*64 + c
    const int t = threadIdx.x;           // 0..63
    const float* base = ppart + (size_t)b * 1024;
    float s = 0.f, qs = 0.f;
    #pragma unroll
    for (int k = 0; k < 8; k++) {
        const int idx = t + 64 * k;
        s  += base[idx * 2];
        qs += base[idx * 2 + 1];
    }
    #pragma unroll
    for (int off = 32; off > 0; off >>= 1) {
        s  += __shfl_xor(s,  off, 64);
        qs += __shfl_xor(qs, off, 64);
    }
    if (t == 0) {
        const int p = b >> 6, c = b & 63;
        const float cnt = 204800.f;      // N*T*V
        const float mean = s / cnt;
        const float var  = qs / cnt - mean * mean;
        const float gw = p ? bn2w[c] : bn1w[c];
        const float gb = p ? bn2b[c] : bn1b[c];
        const float scale = gw * rsqrtf(var + 1e-5f);
        ss[b * 2]     = scale;
        ss[b * 2 + 1] = gb - mean * scale;
    }
}

// ---------------------------------------------------------------------------
// K5: y = relu(z*scale + shift + x), float4-wide, u32 index math.
// ---------------------------------------------------------------------------
__global__ __launch_bounds__(256) void k5_apply(
    const float* __restrict__ x1, const float* __restrict__ x2,
    const unsigned short* __restrict__ z, const float* __restrict__ ss,
    float* __restrict__ out)
{
    const unsigned int g = blockIdx.x * 256u + threadIdx.x;
    const unsigned int e = g * 4u;
    const int p = (e >= 13107200u) ? 1 : 0;
    const unsigned int c = (e / 6400u) & 63u;
    const float* xsrc = p ? x2 : x1;
    const f32x4 xv = *(const f32x4*)(xsrc + (e - (unsigned int)p * 13107200u));
    const s16x4 zv = *(const s16x4*)(const void*)(z + e);
    const float scale = ss[(p * 64 + c) * 2];
    const float shift = ss[(p * 64 + c) * 2 + 1];
    f32x4 o;
    #pragma unroll
    for (int k = 0; k < 4; k++) {
        const float zf = bf2f((unsigned short)zv[k]);
        const float y = zf * scale + shift + xv[k];
        o[k] = y > 0.f ? y : 0.f;
    }
    *(f32x4*)(out + e) = o;
}

// ---------------------------------------------------------------------------
extern "C" void kernel_launch(void* const* d_in, const int* in_sizes, int n_in,
                              void* d_out, int out_size, void* d_ws, size_t ws_size,
                              hipStream_t stream)
{
    (void)in_sizes; (void)n_in; (void)out_size; (void)ws_size;
    const float* x1   = (const float*)d_in[0];
    const float* x2   = (const float*)d_in[1];
    const float* PA   = (const float*)d_in[2];
    const float* alp  = (const float*)d_in[3];
    const float* c1w  = (const float*)d_in[4];
    const float* c1b  = (const float*)d_in[5];
    const float* c2w  = (const float*)d_in[6];
    const float* c2b  = (const float*)d_in[7];
    const float* c3w  = (const float*)d_in[8];
    const float* c3b  = (const float*)d_in[9];
    const float* c4w  = (const float*)d_in[10];
    const float* c4b  = (const float*)d_in[11];
    const float* c5w  = (const float*)d_in[12];
    const float* c5b  = (const float*)d_in[13];
    const float* c6w  = (const float*)d_in[14];
    const float* c6b  = (const float*)d_in[15];
    const float* bn1w = (const float*)d_in[16];
    const float* bn1b = (const float*)d_in[17];
    const float* bn2w = (const float*)d_in[18];
    const float* bn2b = (const float*)d_in[19];

    char* ws = (char*)d_ws;
    unsigned short* aw    = (unsigned short*)(ws + 0);            // 25,165,824 B
    unsigned short* xT    = (unsigned short*)(ws + 25165824);     // 52,428,800 B
    unsigned short* zbuf  = (unsigned short*)(ws + 77594624);     // 52,428,800 B
    float*          ppart = (float*)(ws + 130023424);             //    524,288 B
    float*          ss    = (float*)(ws + 130547712);             //      1,024 B
    unsigned short* awW   = (unsigned short*)(ws + 130548736);    //     49,152 B
    // xmp (13,107,200 B) aliases zbuf[0..13.1MB]; relg (1,929,216 B) aliases
    // zbuf[13.1..15.1MB]. Both consumed before kF writes z (stream-ordered).
    float*          xmp   = (float*)zbuf;
    float*          relg  = (float*)(ws + 77594624 + 13107200);
    // total 130,597,888 B <= 131,041,344 proven budget

    kT_transpose<<<dim3(32, 32, 2), 256, 0, stream>>>(x1, x2, xmp, xT);
    k2a_rel<<<102, 256, 0, stream>>>(xmp, c1w, c1b, c2w, c2b, relg,
                                     c3w, c4w, awW);
    k2b_pack<<<1536, 256, 0, stream>>>(relg, PA, alp, c5w, c5b, c6w, c6b, aw);
    kF_main<<<dim3(4096), 256, 0, stream>>>(xT, c3b, c4b, awW, aw,
                                            zbuf, ppart);
    k4_finalize<<<128, 64, 0, stream>>>(ppart, bn1w, bn1b, bn2w, bn2b, ss);
    k5_apply<<<25600, 256, 0, stream>>>(x1, x2, zbuf, ss, (float*)d_out);
}

// Round 9
// 357.378 us; speedup vs baseline: 1.0758x; 1.0758x over previous
//
#include <hip/hip_runtime.h>
#include <hip/hip_bf16.h>

typedef float  f32x4  __attribute__((ext_vector_type(4)));
typedef short  bf16x8 __attribute__((ext_vector_type(8)));
typedef short  s16x4  __attribute__((ext_vector_type(4)));

// HW bf16 converts (RNE) — used in kT/k2 (measured good in R2).
__device__ __forceinline__ unsigned short f2bf(float f) {
    __hip_bfloat16 h = __float2bfloat16(f);
    return *reinterpret_cast<unsigned short*>(&h);
}
__device__ __forceinline__ unsigned int f2bf2(float a, float b) {
    __hip_bfloat162 h = __float22bfloat162_rn(make_float2(a, b));
    return *reinterpret_cast<unsigned int*>(&h);
}
// Manual RNE bit-trick — used in kF (part of the measured-62µs structure).
__device__ __forceinline__ unsigned short f2bf_bit(float f) {
    unsigned int u = __float_as_uint(f);
    unsigned int r = (u + 0x7FFFu + ((u >> 16) & 1u)) >> 16;
    return (unsigned short)r;
}
__device__ __forceinline__ float bf2f(unsigned short h) {
    return __uint_as_float(((unsigned int)h) << 16);
}

// ---------------------------------------------------------------------------
// KT: x (fp32 [c][pos]) -> xT (bf16 [pos][c], channel-last) + t-mean PARTIALS
// (no atomics). grid (32,32,2), 256 thr. LDS stride 226.
// ---------------------------------------------------------------------------
__global__ __launch_bounds__(256) void kT_transpose(
    const float* __restrict__ x1, const float* __restrict__ x2,
    float* __restrict__ xmp, unsigned short* __restrict__ xT)
{
    const int tc = blockIdx.x, n = blockIdx.y, p = blockIdx.z;
    const float* __restrict__ x = p ? x2 : x1;
    __shared__ unsigned short tile[64 * 226];   // [c][pos 200, stride 226]
    const int tid = threadIdx.x;

    const size_t xb = (size_t)n * 409600 + (size_t)tc * 200;
    for (int k = 0; k < 13; k++) {
        const int idx = tid + k * 256;
        if (idx < 3200) {
            const int c = idx / 50, l = idx % 50;
            const f32x4 v = *(const f32x4*)(x + xb + (size_t)c * 6400 + l * 4);
            unsigned int* dst = (unsigned int*)&tile[c * 226 + l * 4];
            dst[0] = f2bf2(v[0], v[1]);
            dst[1] = f2bf2(v[2], v[3]);
        }
    }
    __syncthreads();

    // mean partials over this chunk's 8 t's -> coalesced row store (no atomics)
    for (int k = 0; k < 7; k++) {
        const int idx = tid + k * 256;
        if (idx < 1600) {
            const int c = idx / 25, v = idx % 25;
            float s = 0.f;
            #pragma unroll
            for (int t = 0; t < 8; t++) s += bf2f(tile[c * 226 + t * 25 + v]);
            xmp[((size_t)((p * 32 + n) * 32 + tc)) * 1600 + idx] =
                s * (1.0f / 256.0f);
        }
    }

    // store phase: gather 8 channels per lane -> coalesced bf16x8 stores
    for (int k = 0; k < 7; k++) {
        const int idx = tid + k * 256;
        if (idx < 1600) {
            const int c8 = idx & 7, pos = idx >> 3;
            bf16x8 o;
            #pragma unroll
            for (int j = 0; j < 8; j++)
                o[j] = (short)tile[(c8 * 8 + j) * 226 + pos];
            *(bf16x8*)(xT + (((size_t)(p * 32 + n) * 6400 + tc * 200 + pos) * 64
                             + c8 * 8)) = o;
        }
    }
}

// ---------------------------------------------------------------------------
// K2a: xmp (32 partials) -> xm -> r1/r2 -> rel -> relg (global, (i,n)-indexed).
// grid 102: blocks 0..95 = (i,n); 96..101 = conv3/conv4 weight pack.
// ---------------------------------------------------------------------------
__global__ __launch_bounds__(256) void k2a_rel(
    const float* __restrict__ xmp,
    const float* __restrict__ c1w, const float* __restrict__ c1b,
    const float* __restrict__ c2w, const float* __restrict__ c2b,
    float* __restrict__ relg,
    const float* __restrict__ c3w, const float* __restrict__ c4w,
    unsigned short* __restrict__ awW)
{
    const int b = blockIdx.x;
    const int tid = threadIdx.x;

    if (b >= 96) {                       // ---- weight pack (6 blocks) ----
        const int pi = b - 96;           // p*3+i
        const int p = pi / 3, i = pi % 3;
        const int cg = tid >> 6, lane = tid & 63, q = lane >> 4, m = lane & 15;
        const float* w3 = p ? c4w : c3w;
        const float* wr = w3 + (size_t)(i * 64 + cg * 16 + m) * 64 + q * 8;
        const f32x4 w00 = *(const f32x4*)(wr);
        const f32x4 w01 = *(const f32x4*)(wr + 4);
        const f32x4 w10 = *(const f32x4*)(wr + 32);
        const f32x4 w11 = *(const f32x4*)(wr + 36);
        bf16x8 af0, af1;
        #pragma unroll
        for (int k = 0; k < 4; k++) {
            af0[k] = (short)f2bf(w00[k]); af0[k + 4] = (short)f2bf(w01[k]);
            af1[k] = (short)f2bf(w10[k]); af1[k + 4] = (short)f2bf(w11[k]);
        }
        unsigned short* o = awW + ((size_t)(pi * 4 + cg) * 64 + lane) * 16;
        *(bf16x8*)(o)     = af0;
        *(bf16x8*)(o + 8) = af1;
        return;
    }

    const int i = b >> 5, n = b & 31;
    __shared__ float xml[3200];
    __shared__ float rl[400];

    // reduce 32 tc-partials (coalesced vec4 rows) -> xm in LDS
    for (int idx = tid; idx < 800; idx += 256) {
        const int p_ = idx / 400, r4 = (idx % 400) * 4;
        f32x4 s = (f32x4){0.f, 0.f, 0.f, 0.f};
        #pragma unroll 4
        for (int tcc = 0; tcc < 32; tcc++)
            s += *(const f32x4*)(xmp + ((size_t)((p_ * 32 + n) * 32 + tcc)) * 1600 + r4);
        *(f32x4*)(xml + p_ * 1600 + r4) = s;
    }
    __syncthreads();

    // r1/r2: 400 dot products of length 64
    for (int idx = tid; idx < 400; idx += 256) {
        const int which = idx / 200;
        const int rr = (idx % 200) / 25;
        const int v = idx % 25;
        const float* wv = (which ? c2w : c1w) + (i * 8 + rr) * 64;
        const float* xp = xml + which * 1600;
        float s = (which ? c2b : c1b)[i * 8 + rr];
        for (int c = 0; c < 64; c++) s += wv[c] * xp[c * 25 + v];
        rl[idx] = s;
    }
    __syncthreads();

    // rel = tanh(r1[u] - r2[v]) -> global, coalesced
    for (int idx = tid; idx < 5000; idx += 256) {
        const int r_ = idx / 625;
        const int rem = idx - r_ * 625;
        const int u = rem / 25;
        const int v = rem - u * 25;
        relg[(size_t)b * 5024 + idx] =
            tanhf(rl[r_ * 25 + u] - rl[200 + r_ * 25 + v]);
    }
}

// ---------------------------------------------------------------------------
// K2b: relg -> a packed as MFMA B-fragments (bf16, zero-padded).
// grid 1536 = (i:3, n:32, pp:2, cq:8); each block packs 8 channels.
// ---------------------------------------------------------------------------
__global__ __launch_bounds__(256) void k2b_pack(
    const float* __restrict__ relg,
    const float* __restrict__ PA, const float* __restrict__ alpha,
    const float* __restrict__ c5w, const float* __restrict__ c5b,
    const float* __restrict__ c6w, const float* __restrict__ c6b,
    unsigned short* __restrict__ aw)
{
    const int b = blockIdx.x;
    const int cq = b & 7;
    const int pp = (b >> 3) & 1;
    const int n  = (b >> 4) & 31;
    const int i  = b >> 9;
    const int tid = threadIdx.x;

    __shared__ float rel[5000];
    const float* rsrc = relg + (size_t)(i * 32 + n) * 5024;
    for (int idx = tid; idx < 1250; idx += 256)
        *(f32x4*)(&rel[idx * 4]) = *(const f32x4*)(rsrc + idx * 4);
    __syncthreads();

    const float al = alpha[0];
    const float* w5 = pp ? c6w : c5w;
    const float* b5 = pp ? c6b : c5b;

    #pragma unroll
    for (int k = 0; k < 4; k++) {
        const int item = tid + k * 256;      // 0..1023
        const int cc = item >> 7;            // 0..7
        const int c  = cq * 8 + cc;
        const int ut = (item >> 6) & 1;
        const int lane = item & 63;
        const int u = ut * 16 + (lane & 15);
        const int qd = lane >> 4;
        bf16x8 outv;
        if (u < 25) {
            float wrow[8];
            #pragma unroll
            for (int r = 0; r < 8; r++) wrow[r] = w5[(i * 64 + c) * 8 + r];
            const float bias = b5[i * 64 + c];
            #pragma unroll
            for (int j = 0; j < 8; j++) {
                const int v = qd * 8 + j;
                float s = 0.f;
                if (v < 25) {
                    s = bias + (pp ? al : PA[i * 625 + u * 25 + v]);
                    #pragma unroll
                    for (int r = 0; r < 8; r++)
                        s += rel[r * 625 + u * 25 + v] * wrow[r];
                }
                outv[j] = (short)f2bf(s);
            }
        } else {
            #pragma unroll
            for (int j = 0; j < 8; j++) outv[j] = 0;
        }
        *(bf16x8*)(aw + ((size_t)((pp * 3 + i) * 32 + n) * 64 + c) * 1024
                      + ut * 512 + lane * 8) = outv;
    }
}

// ---------------------------------------------------------------------------
// KF v7: R7-proven structure (62.7 µs) + one safe barrier elimination.
//  - hoisted xT fragments + lb(256,3) => VGPR 84. R8 PROVED this is the load-
//    batching optimum: capping at 64 VGPR (lb(256,4)) serializes stage1 loads
//    (62.7 -> 97.4 µs despite occupancy 28 -> 40%). Occupancy is NOT the
//    lever; in-flight loads are. Do not lower the register budget again.
//  - single 16 KB X3s (R7: same speed as dbuf, frees LDS).
//  - epilogue staging rebased to w*2048 == each wave's own stage-2 read
//    region => wave-private => the post-stage2(i=2) barrier is droppable
//    (7 -> 6 barriers).
// ---------------------------------------------------------------------------
__global__ __launch_bounds__(256, 3) void kF_main(
    const unsigned short* __restrict__ xT,
    const float* __restrict__ c3b, const float* __restrict__ c4b,
    const unsigned short* __restrict__ awW,
    const unsigned short* __restrict__ aw,
    unsigned short* __restrict__ z,
    float* __restrict__ ppart)
{
    // XCD-aware decode (bijective): xcd = flat&7 under round-robin dispatch.
    const int flat = blockIdx.x;
    const int lidx = flat >> 3;                      // 0..511
    const int grp  = (flat & 7) * 8 + (lidx >> 6);   // 0..63 = (n,p) group
    const int within = lidx & 63;
    const int tc = within & 15, cg = within >> 4;
    const int n = grp & 31, p = grp >> 5;

    __shared__ unsigned short X3s[16 * 512];         // single buffer, 16 KB
    const int tid = threadIdx.x, w = tid >> 6, lane = tid & 63;
    const int q = lane >> 4, m = lane & 15;

    {   // zero once: provides v=25..31 zero padding forever
        int* xi = (int*)X3s;
        #pragma unroll
        for (int k = 0; k < 16; k++) xi[tid + k * 256] = 0;
    }

    const float* __restrict__ b3 = p ? c4b : c3b;
    const size_t xTb = ((size_t)(p * 32 + n) * 6400 + (size_t)tc * 400) * 64;

    // ---- hoist xT fragments into registers (i-invariant) ----
    bf16x8 xr0[7], xr1[7];
    #pragma unroll
    for (int k = 0; k < 7; k++) {
        const int g = w + 4 * k;
        if (g < 25) {
            const unsigned short* xp = xT + xTb + (size_t)(g * 16 + m) * 64 + q * 8;
            xr0[k] = *(const bf16x8*)(xp);
            xr1[k] = *(const bf16x8*)(xp + 32);
        }
    }

    f32x4 acc[4][2];
    #pragma unroll
    for (int a = 0; a < 4; a++) {
        acc[a][0] = (f32x4){0.f, 0.f, 0.f, 0.f};
        acc[a][1] = (f32x4){0.f, 0.f, 0.f, 0.f};
    }

    __syncthreads();   // zero-fill visible to all waves

    for (int i = 0; i < 3; i++) {
        // ---- prefetch stage-2 B-fragments (consumed after the barrier) ----
        bf16x8 B0[4], B1[4];
        #pragma unroll
        for (int cl4 = 0; cl4 < 4; cl4++) {
            const int c = cg * 16 + w * 4 + cl4;
            const unsigned short* ab =
                aw + ((size_t)((p * 3 + i) * 32 + n) * 64 + c) * 1024 + lane * 8;
            B0[cl4] = *(const bf16x8*)(ab);
            B1[cl4] = *(const bf16x8*)(ab + 512);
        }

        // ---- stage 1: X3 = W3*x + b, xT operands already in registers ----
        const unsigned short* wp =
            awW + ((size_t)((p * 3 + i) * 4 + cg) * 64 + lane) * 16;
        const bf16x8 af0 = *(const bf16x8*)(wp);
        const bf16x8 af1 = *(const bf16x8*)(wp + 8);
        float bb[4];
        #pragma unroll
        for (int r = 0; r < 4; r++) bb[r] = b3[i * 64 + cg * 16 + q * 4 + r];

        #pragma unroll
        for (int k = 0; k < 7; k++) {
            const int g = w + 4 * k;
            if (g < 25) {
                f32x4 d = (f32x4){0.f, 0.f, 0.f, 0.f};
                d = __builtin_amdgcn_mfma_f32_16x16x32_bf16(af0, xr0[k], d, 0, 0, 0);
                d = __builtin_amdgcn_mfma_f32_16x16x32_bf16(af1, xr1[k], d, 0, 0, 0);
                const int pos = g * 16 + m;
                const int t = pos / 25, v = pos - t * 25;
                #pragma unroll
                for (int r = 0; r < 4; r++)
                    X3s[(q * 4 + r) * 512 + t * 32 + v] = f2bf_bit(d[r] + bb[r]);
            }
        }
        __syncthreads();

        // ---- stage 2: Z[c][t][u] += X3[c][t][v] * a[c][u][v] ----
        #pragma unroll
        for (int cl4 = 0; cl4 < 4; cl4++) {
            const int cl = w * 4 + cl4;
            const bf16x8 A = *(const bf16x8*)(X3s + cl * 512 + m * 32 + q * 8);
            acc[cl4][0] = __builtin_amdgcn_mfma_f32_16x16x32_bf16(A, B0[cl4], acc[cl4][0], 0, 0, 0);
            acc[cl4][1] = __builtin_amdgcn_mfma_f32_16x16x32_bf16(A, B1[cl4], acc[cl4][1], 0, 0, 0);
        }
        // barrier needed only if X3s gets rewritten (next i's stage1 writes
        // all wave regions). After the LAST stage2 the epilogue writes only
        // wave-private regions identical to each wave's stage-2 read region,
        // so no barrier is required there.
        if (i < 2) __syncthreads();
    }

    // ---- epilogue: stats partials + coalesced z store via LDS transpose ----
    // staging region per wave: [w*2048, w*2048+1600) u16 — subset of the
    // wave's own stage-2 read region [w*2048, (w+1)*2048).
    unsigned short* stg = X3s;
    #pragma unroll
    for (int cl4 = 0; cl4 < 4; cl4++) {
        float sum = 0.f, ssq = 0.f;
        #pragma unroll
        for (int r = 0; r < 4; r++) {
            const float v0 = acc[cl4][0][r];
            sum += v0; ssq += v0 * v0;
        }
        if (m < 9) {
            #pragma unroll
            for (int r = 0; r < 4; r++) {
                const float v1 = acc[cl4][1][r];
                sum += v1; ssq += v1 * v1;
            }
        }
        #pragma unroll
        for (int off = 32; off > 0; off >>= 1) {
            sum += __shfl_xor(sum, off, 64);
            ssq += __shfl_xor(ssq, off, 64);
        }
        const int c = cg * 16 + w * 4 + cl4;
        if (lane == 0) {
            float* pp = ppart + ((size_t)(p * 64 + c) * 512 + n * 16 + tc) * 2;
            pp[0] = sum; pp[1] = ssq;
        }
        // scatter into wave-private staging (own stage-2 region: no barrier)
        #pragma unroll
        for (int ut = 0; ut < 2; ut++) {
            if (ut == 0 || m < 9) {
                #pragma unroll
                for (int r = 0; r < 4; r++)
                    stg[w * 2048 + cl4 * 400 + (q * 4 + r) * 25 + ut * 16 + m] =
                        f2bf_bit(acc[cl4][ut][r]);
            }
        }
    }
    // coalesced read-back + 16B global stores (wave-private region)
    for (int rd = 0; rd < 4; rd++) {
        const int idx = rd * 64 + lane;
        if (idx < 200) {
            const int cl4 = idx / 50, oct = idx % 50;
            const bf16x8 vz = *(const bf16x8*)(stg + w * 2048 + cl4 * 400 + oct * 8);
            const int c = cg * 16 + w * 4 + cl4;
            *(bf16x8*)(z + ((size_t)((p * 32 + n) * 64 + c)) * 6400
                         + tc * 400 + oct * 8) = vz;
        }
    }
}

// ---------------------------------------------------------------------------
// K4: reduce ppart (512 partials per (p,c)) -> per-channel scale/shift.
// ---------------------------------------------------------------------------
__global__ void k4_finalize(const float* __restrict__ ppart,
                            const float* __restrict__ bn1w, const float* __restrict__ bn1b,
                            const float* __restrict__ bn2w, const float* __restrict__ bn2b,
                            float* __restrict__ ss)
{
    const int b = blockIdx.x;            // p*64 + c
    const int t = threadIdx.x;           // 0..63
    const float* base = ppart + (size_t)b * 1024;
    float s = 0.f, qs = 0.f;
    #pragma unroll
    for (int k = 0; k < 8; k++) {
        const int idx = t + 64 * k;
        s  += base[idx * 2];
        qs += base[idx * 2 + 1];
    }
    #pragma unroll
    for (int off = 32; off > 0; off >>= 1) {
        s  += __shfl_xor(s,  off, 64);
        qs += __shfl_xor(qs, off, 64);
    }
    if (t == 0) {
        const int p = b >> 6, c = b & 63;
        const float cnt = 204800.f;      // N*T*V
        const float mean = s / cnt;
        const float var  = qs / cnt - mean * mean;
        const float gw = p ? bn2w[c] : bn1w[c];
        const float gb = p ? bn2b[c] : bn1b[c];
        const float scale = gw * rsqrtf(var + 1e-5f);
        ss[b * 2]     = scale;
        ss[b * 2 + 1] = gb - mean * scale;
    }
}

// ---------------------------------------------------------------------------
// K5: y = relu(z*scale + shift + x), float4-wide, u32 index math.
// ---------------------------------------------------------------------------
__global__ __launch_bounds__(256) void k5_apply(
    const float* __restrict__ x1, const float* __restrict__ x2,
    const unsigned short* __restrict__ z, const float* __restrict__ ss,
    float* __restrict__ out)
{
    const unsigned int g = blockIdx.x * 256u + threadIdx.x;
    const unsigned int e = g * 4u;
    const int p = (e >= 13107200u) ? 1 : 0;
    const unsigned int c = (e / 6400u) & 63u;
    const float* xsrc = p ? x2 : x1;
    const f32x4 xv = *(const f32x4*)(xsrc + (e - (unsigned int)p * 13107200u));
    const s16x4 zv = *(const s16x4*)(const void*)(z + e);
    const float scale = ss[(p * 64 + c) * 2];
    const float shift = ss[(p * 64 + c) * 2 + 1];
    f32x4 o;
    #pragma unroll
    for (int k = 0; k < 4; k++) {
        const float zf = bf2f((unsigned short)zv[k]);
        const float y = zf * scale + shift + xv[k];
        o[k] = y > 0.f ? y : 0.f;
    }
    *(f32x4*)(out + e) = o;
}

// ---------------------------------------------------------------------------
extern "C" void kernel_launch(void* const* d_in, const int* in_sizes, int n_in,
                              void* d_out, int out_size, void* d_ws, size_t ws_size,
                              hipStream_t stream)
{
    (void)in_sizes; (void)n_in; (void)out_size; (void)ws_size;
    const float* x1   = (const float*)d_in[0];
    const float* x2   = (const float*)d_in[1];
    const float* PA   = (const float*)d_in[2];
    const float* alp  = (const float*)d_in[3];
    const float* c1w  = (const float*)d_in[4];
    const float* c1b  = (const float*)d_in[5];
    const float* c2w  = (const float*)d_in[6];
    const float* c2b  = (const float*)d_in[7];
    const float* c3w  = (const float*)d_in[8];
    const float* c3b  = (const float*)d_in[9];
    const float* c4w  = (const float*)d_in[10];
    const float* c4b  = (const float*)d_in[11];
    const float* c5w  = (const float*)d_in[12];
    const float* c5b  = (const float*)d_in[13];
    const float* c6w  = (const float*)d_in[14];
    const float* c6b  = (const float*)d_in[15];
    const float* bn1w = (const float*)d_in[16];
    const float* bn1b = (const float*)d_in[17];
    const float* bn2w = (const float*)d_in[18];
    const float* bn2b = (const float*)d_in[19];

    char* ws = (char*)d_ws;
    unsigned short* aw    = (unsigned short*)(ws + 0);            // 25,165,824 B
    unsigned short* xT    = (unsigned short*)(ws + 25165824);     // 52,428,800 B
    unsigned short* zbuf  = (unsigned short*)(ws + 77594624);     // 52,428,800 B
    float*          ppart = (float*)(ws + 130023424);             //    524,288 B
    float*          ss    = (float*)(ws + 130547712);             //      1,024 B
    unsigned short* awW   = (unsigned short*)(ws + 130548736);    //     49,152 B
    // xmp (13,107,200 B) aliases zbuf[0..13.1MB]; relg (1,929,216 B) aliases
    // zbuf[13.1..15.1MB]. Both consumed before kF writes z (stream-ordered).
    float*          xmp   = (float*)zbuf;
    float*          relg  = (float*)(ws + 77594624 + 13107200);
    // total 130,597,888 B <= 131,041,344 proven budget

    kT_transpose<<<dim3(32, 32, 2), 256, 0, stream>>>(x1, x2, xmp, xT);
    k2a_rel<<<102, 256, 0, stream>>>(xmp, c1w, c1b, c2w, c2b, relg,
                                     c3w, c4w, awW);
    k2b_pack<<<1536, 256, 0, stream>>>(relg, PA, alp, c5w, c5b, c6w, c6b, aw);
    kF_main<<<dim3(4096), 256, 0, stream>>>(xT, c3b, c4b, awW, aw,
                                            zbuf, ppart);
    k4_finalize<<<128, 64, 0, stream>>>(ppart, bn1w, bn1b, bn2w, bn2b, ss);
    k5_apply<<<25600, 256, 0, stream>>>(x1, x2, zbuf, ss, (float*)d_out);
}

// Round 10
// 352.401 us; speedup vs baseline: 1.0910x; 1.0141x over previous
//
#include <hip/hip_runtime.h>
#include <hip/hip_bf16.h>

typedef float  f32x4  __attribute__((ext_vector_type(4)));
typedef short  bf16x8 __attribute__((ext_vector_type(8)));
typedef short  s16x4  __attribute__((ext_vector_type(4)));

// HW bf16 converts (RNE) — used in kT/k2 (measured good in R2).
__device__ __forceinline__ unsigned short f2bf(float f) {
    __hip_bfloat16 h = __float2bfloat16(f);
    return *reinterpret_cast<unsigned short*>(&h);
}
__device__ __forceinline__ unsigned int f2bf2(float a, float b) {
    __hip_bfloat162 h = __float22bfloat162_rn(make_float2(a, b));
    return *reinterpret_cast<unsigned int*>(&h);
}
// Manual RNE bit-trick — used in kF (part of the measured-62µs structure).
__device__ __forceinline__ unsigned short f2bf_bit(float f) {
    unsigned int u = __float_as_uint(f);
    unsigned int r = (u + 0x7FFFu + ((u >> 16) & 1u)) >> 16;
    return (unsigned short)r;
}
__device__ __forceinline__ float bf2f(unsigned short h) {
    return __uint_as_float(((unsigned int)h) << 16);
}

// ---------------------------------------------------------------------------
// KT: x (fp32 [c][pos]) -> xT (bf16 [pos][c], channel-last) + t-mean PARTIALS
// (no atomics). grid (32,32,2), 256 thr. LDS stride 226.
// ---------------------------------------------------------------------------
__global__ __launch_bounds__(256) void kT_transpose(
    const float* __restrict__ x1, const float* __restrict__ x2,
    float* __restrict__ xmp, unsigned short* __restrict__ xT)
{
    const int tc = blockIdx.x, n = blockIdx.y, p = blockIdx.z;
    const float* __restrict__ x = p ? x2 : x1;
    __shared__ unsigned short tile[64 * 226];   // [c][pos 200, stride 226]
    const int tid = threadIdx.x;

    const size_t xb = (size_t)n * 409600 + (size_t)tc * 200;
    for (int k = 0; k < 13; k++) {
        const int idx = tid + k * 256;
        if (idx < 3200) {
            const int c = idx / 50, l = idx % 50;
            const f32x4 v = *(const f32x4*)(x + xb + (size_t)c * 6400 + l * 4);
            unsigned int* dst = (unsigned int*)&tile[c * 226 + l * 4];
            dst[0] = f2bf2(v[0], v[1]);
            dst[1] = f2bf2(v[2], v[3]);
        }
    }
    __syncthreads();

    // mean partials over this chunk's 8 t's -> coalesced row store (no atomics)
    for (int k = 0; k < 7; k++) {
        const int idx = tid + k * 256;
        if (idx < 1600) {
            const int c = idx / 25, v = idx % 25;
            float s = 0.f;
            #pragma unroll
            for (int t = 0; t < 8; t++) s += bf2f(tile[c * 226 + t * 25 + v]);
            xmp[((size_t)((p * 32 + n) * 32 + tc)) * 1600 + idx] =
                s * (1.0f / 256.0f);
        }
    }

    // store phase: gather 8 channels per lane -> coalesced bf16x8 stores
    for (int k = 0; k < 7; k++) {
        const int idx = tid + k * 256;
        if (idx < 1600) {
            const int c8 = idx & 7, pos = idx >> 3;
            bf16x8 o;
            #pragma unroll
            for (int j = 0; j < 8; j++)
                o[j] = (short)tile[(c8 * 8 + j) * 226 + pos];
            *(bf16x8*)(xT + (((size_t)(p * 32 + n) * 6400 + tc * 200 + pos) * 64
                             + c8 * 8)) = o;
        }
    }
}

// ---------------------------------------------------------------------------
// K2a: xmp (32 partials) -> xm -> r1/r2 -> rel -> relg (global, (i,n)-indexed).
// grid 102: blocks 0..95 = (i,n); 96..101 = conv3/conv4 weight pack.
// ---------------------------------------------------------------------------
__global__ __launch_bounds__(256) void k2a_rel(
    const float* __restrict__ xmp,
    const float* __restrict__ c1w, const float* __restrict__ c1b,
    const float* __restrict__ c2w, const float* __restrict__ c2b,
    float* __restrict__ relg,
    const float* __restrict__ c3w, const float* __restrict__ c4w,
    unsigned short* __restrict__ awW)
{
    const int b = blockIdx.x;
    const int tid = threadIdx.x;

    if (b >= 96) {                       // ---- weight pack (6 blocks) ----
        const int pi = b - 96;           // p*3+i
        const int p = pi / 3, i = pi % 3;
        const int cg = tid >> 6, lane = tid & 63, q = lane >> 4, m = lane & 15;
        const float* w3 = p ? c4w : c3w;
        const float* wr = w3 + (size_t)(i * 64 + cg * 16 + m) * 64 + q * 8;
        const f32x4 w00 = *(const f32x4*)(wr);
        const f32x4 w01 = *(const f32x4*)(wr + 4);
        const f32x4 w10 = *(const f32x4*)(wr + 32);
        const f32x4 w11 = *(const f32x4*)(wr + 36);
        bf16x8 af0, af1;
        #pragma unroll
        for (int k = 0; k < 4; k++) {
            af0[k] = (short)f2bf(w00[k]); af0[k + 4] = (short)f2bf(w01[k]);
            af1[k] = (short)f2bf(w10[k]); af1[k + 4] = (short)f2bf(w11[k]);
        }
        unsigned short* o = awW + ((size_t)(pi * 4 + cg) * 64 + lane) * 16;
        *(bf16x8*)(o)     = af0;
        *(bf16x8*)(o + 8) = af1;
        return;
    }

    const int i = b >> 5, n = b & 31;
    __shared__ float xml[3200];
    __shared__ float rl[400];

    // reduce 32 tc-partials (coalesced vec4 rows) -> xm in LDS
    for (int idx = tid; idx < 800; idx += 256) {
        const int p_ = idx / 400, r4 = (idx % 400) * 4;
        f32x4 s = (f32x4){0.f, 0.f, 0.f, 0.f};
        #pragma unroll 4
        for (int tcc = 0; tcc < 32; tcc++)
            s += *(const f32x4*)(xmp + ((size_t)((p_ * 32 + n) * 32 + tcc)) * 1600 + r4);
        *(f32x4*)(xml + p_ * 1600 + r4) = s;
    }
    __syncthreads();

    // r1/r2: 400 dot products of length 64
    for (int idx = tid; idx < 400; idx += 256) {
        const int which = idx / 200;
        const int rr = (idx % 200) / 25;
        const int v = idx % 25;
        const float* wv = (which ? c2w : c1w) + (i * 8 + rr) * 64;
        const float* xp = xml + which * 1600;
        float s = (which ? c2b : c1b)[i * 8 + rr];
        for (int c = 0; c < 64; c++) s += wv[c] * xp[c * 25 + v];
        rl[idx] = s;
    }
    __syncthreads();

    // rel = tanh(r1[u] - r2[v]) -> global, coalesced
    for (int idx = tid; idx < 5000; idx += 256) {
        const int r_ = idx / 625;
        const int rem = idx - r_ * 625;
        const int u = rem / 25;
        const int v = rem - u * 25;
        relg[(size_t)b * 5024 + idx] =
            tanhf(rl[r_ * 25 + u] - rl[200 + r_ * 25 + v]);
    }
}

// ---------------------------------------------------------------------------
// K2b: relg -> a packed as MFMA B-fragments (bf16, zero-padded).
// grid 1536 = (i:3, n:32, pp:2, cq:8); each block packs 8 channels.
// ---------------------------------------------------------------------------
__global__ __launch_bounds__(256) void k2b_pack(
    const float* __restrict__ relg,
    const float* __restrict__ PA, const float* __restrict__ alpha,
    const float* __restrict__ c5w, const float* __restrict__ c5b,
    const float* __restrict__ c6w, const float* __restrict__ c6b,
    unsigned short* __restrict__ aw)
{
    const int b = blockIdx.x;
    const int cq = b & 7;
    const int pp = (b >> 3) & 1;
    const int n  = (b >> 4) & 31;
    const int i  = b >> 9;
    const int tid = threadIdx.x;

    __shared__ float rel[5000];
    const float* rsrc = relg + (size_t)(i * 32 + n) * 5024;
    for (int idx = tid; idx < 1250; idx += 256)
        *(f32x4*)(&rel[idx * 4]) = *(const f32x4*)(rsrc + idx * 4);
    __syncthreads();

    const float al = alpha[0];
    const float* w5 = pp ? c6w : c5w;
    const float* b5 = pp ? c6b : c5b;

    #pragma unroll
    for (int k = 0; k < 4; k++) {
        const int item = tid + k * 256;      // 0..1023
        const int cc = item >> 7;            // 0..7
        const int c  = cq * 8 + cc;
        const int ut = (item >> 6) & 1;
        const int lane = item & 63;
        const int u = ut * 16 + (lane & 15);
        const int qd = lane >> 4;
        bf16x8 outv;
        if (u < 25) {
            float wrow[8];
            #pragma unroll
            for (int r = 0; r < 8; r++) wrow[r] = w5[(i * 64 + c) * 8 + r];
            const float bias = b5[i * 64 + c];
            #pragma unroll
            for (int j = 0; j < 8; j++) {
                const int v = qd * 8 + j;
                float s = 0.f;
                if (v < 25) {
                    s = bias + (pp ? al : PA[i * 625 + u * 25 + v]);
                    #pragma unroll
                    for (int r = 0; r < 8; r++)
                        s += rel[r * 625 + u * 25 + v] * wrow[r];
                }
                outv[j] = (short)f2bf(s);
            }
        } else {
            #pragma unroll
            for (int j = 0; j < 8; j++) outv[j] = 0;
        }
        *(bf16x8*)(aw + ((size_t)((pp * 3 + i) * 32 + n) * 64 + c) * 1024
                      + ut * 512 + lane * 8) = outv;
    }
}

// ---------------------------------------------------------------------------
// KF v5 (R7-EXACT, measured 62.7 µs): single 16 KB X3s, hoisted xT fragments,
// lb(256,3) => VGPR 84. Frozen structure — every probe off this point lost:
//   R2 pipeline/swizzle 77, R3 lb(256,4)+hoist spills 131, R8 64VGPR in-loop
//   loads 97, R9 conditional-barrier "safe" elision 73 (codegen perturbation).
// Unconditional barriers, staging w*1600. Do not edit without a full bench.
// ---------------------------------------------------------------------------
__global__ __launch_bounds__(256, 3) void kF_main(
    const unsigned short* __restrict__ xT,
    const float* __restrict__ c3b, const float* __restrict__ c4b,
    const unsigned short* __restrict__ awW,
    const unsigned short* __restrict__ aw,
    unsigned short* __restrict__ z,
    float* __restrict__ ppart)
{
    // XCD-aware decode (bijective): xcd = flat&7 under round-robin dispatch.
    const int flat = blockIdx.x;
    const int lidx = flat >> 3;                      // 0..511
    const int grp  = (flat & 7) * 8 + (lidx >> 6);   // 0..63 = (n,p) group
    const int within = lidx & 63;
    const int tc = within & 15, cg = within >> 4;
    const int n = grp & 31, p = grp >> 5;

    __shared__ unsigned short X3s[16 * 512];         // single buffer, 16 KB
    const int tid = threadIdx.x, w = tid >> 6, lane = tid & 63;
    const int q = lane >> 4, m = lane & 15;

    {   // zero once: provides v=25..31 zero padding forever
        int* xi = (int*)X3s;
        #pragma unroll
        for (int k = 0; k < 16; k++) xi[tid + k * 256] = 0;
    }

    const float* __restrict__ b3 = p ? c4b : c3b;
    const size_t xTb = ((size_t)(p * 32 + n) * 6400 + (size_t)tc * 400) * 64;

    // ---- hoist xT fragments into registers (i-invariant) ----
    bf16x8 xr0[7], xr1[7];
    #pragma unroll
    for (int k = 0; k < 7; k++) {
        const int g = w + 4 * k;
        if (g < 25) {
            const unsigned short* xp = xT + xTb + (size_t)(g * 16 + m) * 64 + q * 8;
            xr0[k] = *(const bf16x8*)(xp);
            xr1[k] = *(const bf16x8*)(xp + 32);
        }
    }

    f32x4 acc[4][2];
    #pragma unroll
    for (int a = 0; a < 4; a++) {
        acc[a][0] = (f32x4){0.f, 0.f, 0.f, 0.f};
        acc[a][1] = (f32x4){0.f, 0.f, 0.f, 0.f};
    }

    __syncthreads();   // zero-fill visible to all waves

    for (int i = 0; i < 3; i++) {
        // ---- prefetch stage-2 B-fragments (consumed after the barrier) ----
        bf16x8 B0[4], B1[4];
        #pragma unroll
        for (int cl4 = 0; cl4 < 4; cl4++) {
            const int c = cg * 16 + w * 4 + cl4;
            const unsigned short* ab =
                aw + ((size_t)((p * 3 + i) * 32 + n) * 64 + c) * 1024 + lane * 8;
            B0[cl4] = *(const bf16x8*)(ab);
            B1[cl4] = *(const bf16x8*)(ab + 512);
        }

        // ---- stage 1: X3 = W3*x + b, xT operands already in registers ----
        const unsigned short* wp =
            awW + ((size_t)((p * 3 + i) * 4 + cg) * 64 + lane) * 16;
        const bf16x8 af0 = *(const bf16x8*)(wp);
        const bf16x8 af1 = *(const bf16x8*)(wp + 8);
        float bb[4];
        #pragma unroll
        for (int r = 0; r < 4; r++) bb[r] = b3[i * 64 + cg * 16 + q * 4 + r];

        #pragma unroll
        for (int k = 0; k < 7; k++) {
            const int g = w + 4 * k;
            if (g < 25) {
                f32x4 d = (f32x4){0.f, 0.f, 0.f, 0.f};
                d = __builtin_amdgcn_mfma_f32_16x16x32_bf16(af0, xr0[k], d, 0, 0, 0);
                d = __builtin_amdgcn_mfma_f32_16x16x32_bf16(af1, xr1[k], d, 0, 0, 0);
                const int pos = g * 16 + m;
                const int t = pos / 25, v = pos - t * 25;
                #pragma unroll
                for (int r = 0; r < 4; r++)
                    X3s[(q * 4 + r) * 512 + t * 32 + v] = f2bf_bit(d[r] + bb[r]);
            }
        }
        __syncthreads();

        // ---- stage 2: Z[c][t][u] += X3[c][t][v] * a[c][u][v] ----
        #pragma unroll
        for (int cl4 = 0; cl4 < 4; cl4++) {
            const int cl = w * 4 + cl4;
            const bf16x8 A = *(const bf16x8*)(X3s + cl * 512 + m * 32 + q * 8);
            acc[cl4][0] = __builtin_amdgcn_mfma_f32_16x16x32_bf16(A, B0[cl4], acc[cl4][0], 0, 0, 0);
            acc[cl4][1] = __builtin_amdgcn_mfma_f32_16x16x32_bf16(A, B1[cl4], acc[cl4][1], 0, 0, 0);
        }
        __syncthreads();   // X3s overwritten next i / reused by epilogue
    }

    // ---- epilogue: stats partials + coalesced z store via LDS transpose ----
    unsigned short* stg = X3s;          // staging: 4 waves x 1600 u16
    #pragma unroll
    for (int cl4 = 0; cl4 < 4; cl4++) {
        float sum = 0.f, ssq = 0.f;
        #pragma unroll
        for (int r = 0; r < 4; r++) {
            const float v0 = acc[cl4][0][r];
            sum += v0; ssq += v0 * v0;
        }
        if (m < 9) {
            #pragma unroll
            for (int r = 0; r < 4; r++) {
                const float v1 = acc[cl4][1][r];
                sum += v1; ssq += v1 * v1;
            }
        }
        #pragma unroll
        for (int off = 32; off > 0; off >>= 1) {
            sum += __shfl_xor(sum, off, 64);
            ssq += __shfl_xor(ssq, off, 64);
        }
        const int c = cg * 16 + w * 4 + cl4;
        if (lane == 0) {
            float* pp = ppart + ((size_t)(p * 64 + c) * 512 + n * 16 + tc) * 2;
            pp[0] = sum; pp[1] = ssq;
        }
        // scatter into wave-private staging (no barrier needed: wave-private)
        #pragma unroll
        for (int ut = 0; ut < 2; ut++) {
            if (ut == 0 || m < 9) {
                #pragma unroll
                for (int r = 0; r < 4; r++)
                    stg[w * 1600 + cl4 * 400 + (q * 4 + r) * 25 + ut * 16 + m] =
                        f2bf_bit(acc[cl4][ut][r]);
            }
        }
    }
    // coalesced read-back + 16B global stores (wave-private region)
    for (int rd = 0; rd < 4; rd++) {
        const int idx = rd * 64 + lane;
        if (idx < 200) {
            const int cl4 = idx / 50, oct = idx % 50;
            const bf16x8 vz = *(const bf16x8*)(stg + w * 1600 + cl4 * 400 + oct * 8);
            const int c = cg * 16 + w * 4 + cl4;
            *(bf16x8*)(z + ((size_t)((p * 32 + n) * 64 + c)) * 6400
                         + tc * 400 + oct * 8) = vz;
        }
    }
}

// ---------------------------------------------------------------------------
// K4: reduce ppart (512 partials per (p,c)) -> per-channel scale/shift.
// ---------------------------------------------------------------------------
__global__ void k4_finalize(const float* __restrict__ ppart,
                            const float* __restrict__ bn1w, const float* __restrict__ bn1b,
                            const float* __restrict__ bn2w, const float* __restrict__ bn2b,
                            float* __restrict__ ss)
{
    const int b = blockIdx.x;            // p*64 + c
    const int t = threadIdx.x;           // 0..63
    const float* base = ppart + (size_t)b * 1024;
    float s = 0.f, qs = 0.f;
    #pragma unroll
    for (int k = 0; k < 8; k++) {
        const int idx = t + 64 * k;
        s  += base[idx * 2];
        qs += base[idx * 2 + 1];
    }
    #pragma unroll
    for (int off = 32; off > 0; off >>= 1) {
        s  += __shfl_xor(s,  off, 64);
        qs += __shfl_xor(qs, off, 64);
    }
    if (t == 0) {
        const int p = b >> 6, c = b & 63;
        const float cnt = 204800.f;      // N*T*V
        const float mean = s / cnt;
        const float var  = qs / cnt - mean * mean;
        const float gw = p ? bn2w[c] : bn1w[c];
        const float gb = p ? bn2b[c] : bn1b[c];
        const float scale = gw * rsqrtf(var + 1e-5f);
        ss[b * 2]     = scale;
        ss[b * 2 + 1] = gb - mean * scale;
    }
}

// ---------------------------------------------------------------------------
// K5: y = relu(z*scale + shift + x), float4-wide, u32 index math.
// ---------------------------------------------------------------------------
__global__ __launch_bounds__(256) void k5_apply(
    const float* __restrict__ x1, const float* __restrict__ x2,
    const unsigned short* __restrict__ z, const float* __restrict__ ss,
    float* __restrict__ out)
{
    const unsigned int g = blockIdx.x * 256u + threadIdx.x;
    const unsigned int e = g * 4u;
    const int p = (e >= 13107200u) ? 1 : 0;
    const unsigned int c = (e / 6400u) & 63u;
    const float* xsrc = p ? x2 : x1;
    const f32x4 xv = *(const f32x4*)(xsrc + (e - (unsigned int)p * 13107200u));
    const s16x4 zv = *(const s16x4*)(const void*)(z + e);
    const float scale = ss[(p * 64 + c) * 2];
    const float shift = ss[(p * 64 + c) * 2 + 1];
    f32x4 o;
    #pragma unroll
    for (int k = 0; k < 4; k++) {
        const float zf = bf2f((unsigned short)zv[k]);
        const float y = zf * scale + shift + xv[k];
        o[k] = y > 0.f ? y : 0.f;
    }
    *(f32x4*)(out + e) = o;
}

// ---------------------------------------------------------------------------
extern "C" void kernel_launch(void* const* d_in, const int* in_sizes, int n_in,
                              void* d_out, int out_size, void* d_ws, size_t ws_size,
                              hipStream_t stream)
{
    (void)in_sizes; (void)n_in; (void)out_size; (void)ws_size;
    const float* x1   = (const float*)d_in[0];
    const float* x2   = (const float*)d_in[1];
    const float* PA   = (const float*)d_in[2];
    const float* alp  = (const float*)d_in[3];
    const float* c1w  = (const float*)d_in[4];
    const float* c1b  = (const float*)d_in[5];
    const float* c2w  = (const float*)d_in[6];
    const float* c2b  = (const float*)d_in[7];
    const float* c3w  = (const float*)d_in[8];
    const float* c3b  = (const float*)d_in[9];
    const float* c4w  = (const float*)d_in[10];
    const float* c4b  = (const float*)d_in[11];
    const float* c5w  = (const float*)d_in[12];
    const float* c5b  = (const float*)d_in[13];
    const float* c6w  = (const float*)d_in[14];
    const float* c6b  = (const float*)d_in[15];
    const float* bn1w = (const float*)d_in[16];
    const float* bn1b = (const float*)d_in[17];
    const float* bn2w = (const float*)d_in[18];
    const float* bn2b = (const float*)d_in[19];

    char* ws = (char*)d_ws;
    unsigned short* aw    = (unsigned short*)(ws + 0);            // 25,165,824 B
    unsigned short* xT    = (unsigned short*)(ws + 25165824);     // 52,428,800 B
    unsigned short* zbuf  = (unsigned short*)(ws + 77594624);     // 52,428,800 B
    float*          ppart = (float*)(ws + 130023424);             //    524,288 B
    float*          ss    = (float*)(ws + 130547712);             //      1,024 B
    unsigned short* awW   = (unsigned short*)(ws + 130548736);    //     49,152 B
    // xmp (13,107,200 B) aliases zbuf[0..13.1MB]; relg (1,929,216 B) aliases
    // zbuf[13.1..15.1MB]. Both consumed before kF writes z (stream-ordered).
    float*          xmp   = (float*)zbuf;
    float*          relg  = (float*)(ws + 77594624 + 13107200);
    // total 130,597,888 B <= 131,041,344 proven budget

    kT_transpose<<<dim3(32, 32, 2), 256, 0, stream>>>(x1, x2, xmp, xT);
    k2a_rel<<<102, 256, 0, stream>>>(xmp, c1w, c1b, c2w, c2b, relg,
                                     c3w, c4w, awW);
    k2b_pack<<<1536, 256, 0, stream>>>(relg, PA, alp, c5w, c5b, c6w, c6b, aw);
    kF_main<<<dim3(4096), 256, 0, stream>>>(xT, c3b, c4b, awW, aw,
                                            zbuf, ppart);
    k4_finalize<<<128, 64, 0, stream>>>(ppart, bn1w, bn1b, bn2w, bn2b, ss);
    k5_apply<<<25600, 256, 0, stream>>>(x1, x2, zbuf, ss, (float*)d_out);
}